// Round 5
// baseline (2621.636 us; speedup 1.0000x reference)
//
#include <hip/hip_runtime.h>
#include <cstddef>
#include <cstdint>

// Problem constants (match reference)
#define NN 50000          // nodes
#define NE 600000         // edges
#define CC 128            // in/out channels
#define HD 256            // MLP hidden
#define NC (NN * CC)      // 6,400,000 floats per [N,C] buffer
#define EPS_GEN 1e-7f
#define EPS_BN  1e-5f

// ---------------------------------------------------------------------------
// Column stats: partial per-column sum/sumsq with per-thread accumulation,
// one atomicAdd pair per thread at the end. Ncols in {128, 256}.
__global__ __launch_bounds__(256)
void stats_kernel(const float* __restrict__ A, int M, int Ncols,
                  float* __restrict__ sum, float* __restrict__ sumsq)
{
    int col = threadIdx.x % Ncols;
    int rowInBlock = threadIdx.x / Ncols;
    int rowsPerBlock = blockDim.x / Ncols;
    int step = rowsPerBlock * gridDim.x;
    float s = 0.f, q = 0.f;
    for (int r = blockIdx.x * rowsPerBlock + rowInBlock; r < M; r += step) {
        float v = A[(size_t)r * Ncols + col];
        s += v;
        q = fmaf(v, v, q);
    }
    atomicAdd(&sum[col], s);
    atomicAdd(&sumsq[col], q);
}

// scale = g * rsqrt(var+eps); shift = b - mean*scale
__global__ void finalize_bn(const float* __restrict__ sum,
                            const float* __restrict__ sumsq,
                            const float* __restrict__ g,
                            const float* __restrict__ b,
                            float* __restrict__ scale,
                            float* __restrict__ shift,
                            int M, int Ncols)
{
    int c = blockIdx.x * blockDim.x + threadIdx.x;
    if (c >= Ncols) return;
    float inv_m = 1.0f / (float)M;
    float mean = sum[c] * inv_m;
    float var  = sumsq[c] * inv_m - mean * mean;
    float v = var + EPS_BN;
    float rs = rsqrtf(v);
    rs = rs * (1.5f - 0.5f * v * rs * rs);   // one Newton step for accuracy
    float sc = g[c] * rs;
    scale[c] = sc;
    shift[c] = b[c] - mean * sc;
}

// h = relu(x*scale + shift), vectorized float4. total = NC/4.
__global__ __launch_bounds__(256)
void bn_relu_kernel(const float* __restrict__ x,
                    const float* __restrict__ scale,
                    const float* __restrict__ shift,
                    float* __restrict__ h, int total)
{
    int tid = blockIdx.x * blockDim.x + threadIdx.x;
    if (tid >= total) return;
    int c4 = tid & (CC / 4 - 1);
    float4 sc = ((const float4*)scale)[c4];
    float4 sh = ((const float4*)shift)[c4];
    float4 v  = ((const float4*)x)[tid];
    float4 o;
    o.x = fmaxf(fmaf(v.x, sc.x, sh.x), 0.f);
    o.y = fmaxf(fmaf(v.y, sc.y, sh.y), 0.f);
    o.z = fmaxf(fmaf(v.z, sc.z, sh.z), 0.f);
    o.w = fmaxf(fmaf(v.w, sc.w, sh.w), 0.f);
    ((float4*)h)[tid] = o;
}

// Softmax-agg without the max shift (msg bounded: softmax shift-invariant).
// den += exp(msg); num += msg*exp(msg).  One thread per (edge, 4 channels).
__global__ __launch_bounds__(256)
void edge_sum_kernel(const int* __restrict__ src, const int* __restrict__ dst,
                     const float* __restrict__ h,
                     float* __restrict__ den, float* __restrict__ num)
{
    int tid = blockIdx.x * blockDim.x + threadIdx.x;
    if (tid >= NE * 32) return;
    int e  = tid >> 5;
    int c4 = tid & 31;
    int s = src[e], d = dst[e];
    float4 hv = ((const float4*)(h + (size_t)s * CC))[c4];
    float* dp = den + (size_t)d * CC + c4 * 4;
    float* np = num + (size_t)d * CC + c4 * 4;
    float msg, ex;
    msg = hv.x + EPS_GEN; ex = __expf(msg);
    atomicAdd(dp + 0, ex); atomicAdd(np + 0, msg * ex);
    msg = hv.y + EPS_GEN; ex = __expf(msg);
    atomicAdd(dp + 1, ex); atomicAdd(np + 1, msg * ex);
    msg = hv.z + EPS_GEN; ex = __expf(msg);
    atomicAdd(dp + 2, ex); atomicAdd(np + 2, msg * ex);
    msg = hv.w + EPS_GEN; ex = __expf(msg);
    atomicAdd(dp + 3, ex); atomicAdd(np + 3, msg * ex);
}

// a0 = num/(den + 1e-16) + h  (root add)
__global__ __launch_bounds__(256)
void agg_kernel(const float* __restrict__ num, const float* __restrict__ den,
                const float* __restrict__ h, float* __restrict__ a0, int total4)
{
    int tid = blockIdx.x * blockDim.x + threadIdx.x;
    if (tid >= total4) return;
    float4 n4 = ((const float4*)num)[tid];
    float4 d4 = ((const float4*)den)[tid];
    float4 h4 = ((const float4*)h)[tid];
    float4 o;
    o.x = n4.x / (d4.x + 1e-16f) + h4.x;
    o.y = n4.y / (d4.y + 1e-16f) + h4.y;
    o.z = n4.z / (d4.z + 1e-16f) + h4.z;
    o.w = n4.w / (d4.w + 1e-16f) + h4.w;
    ((float4*)a0)[tid] = o;
}

// ---------------------------------------------------------------------------
// fp32 tiled GEMM: C[M,Nn] = op(A)[M,K] @ B[K,Nn] + bias (+ resid)
// op(A) = relu(A*asc[k] + ash[k]) if TRANSA (fused BN+ReLU on the A operand).
// 64x64 tile, BK=32, 256 threads, 4x4 per thread.
template <bool TRANSA, bool RESID>
__global__ __launch_bounds__(256)
void gemm_k(const float* __restrict__ A, const float* __restrict__ B,
            const float* __restrict__ bias,
            const float* __restrict__ asc, const float* __restrict__ ash,
            const float* __restrict__ resid,
            float* __restrict__ Co, int M, int K, int Nn)
{
    __shared__ float As[32][68];   // [k][m], pad 4 -> aligned float4 reads, low conflicts
    __shared__ float Bs[32][64];   // [k][n]
    const int bm = blockIdx.y * 64, bn = blockIdx.x * 64;
    const int tx = threadIdx.x & 15, ty = threadIdx.x >> 4;
    float acc[4][4] = {};

    for (int k0 = 0; k0 < K; k0 += 32) {
        #pragma unroll
        for (int i = 0; i < 8; i++) {
            int m  = (threadIdx.x >> 5) + i * 8;
            int kk = threadIdx.x & 31;
            int row = bm + m;
            float v = 0.f;
            if (row < M) {
                v = A[(size_t)row * K + k0 + kk];
                if (TRANSA) v = fmaxf(fmaf(v, asc[k0 + kk], ash[k0 + kk]), 0.f);
            }
            As[kk][m] = v;
        }
        #pragma unroll
        for (int i = 0; i < 8; i++) {
            int kk = (threadIdx.x >> 6) + i * 4;
            int n  = threadIdx.x & 63;
            Bs[kk][n] = B[(size_t)(k0 + kk) * Nn + bn + n];
        }
        __syncthreads();
        #pragma unroll
        for (int kk = 0; kk < 32; kk++) {
            float4 a = *(const float4*)&As[kk][ty * 4];
            float4 b = *(const float4*)&Bs[kk][tx * 4];
            acc[0][0] = fmaf(a.x, b.x, acc[0][0]);
            acc[0][1] = fmaf(a.x, b.y, acc[0][1]);
            acc[0][2] = fmaf(a.x, b.z, acc[0][2]);
            acc[0][3] = fmaf(a.x, b.w, acc[0][3]);
            acc[1][0] = fmaf(a.y, b.x, acc[1][0]);
            acc[1][1] = fmaf(a.y, b.y, acc[1][1]);
            acc[1][2] = fmaf(a.y, b.z, acc[1][2]);
            acc[1][3] = fmaf(a.y, b.w, acc[1][3]);
            acc[2][0] = fmaf(a.z, b.x, acc[2][0]);
            acc[2][1] = fmaf(a.z, b.y, acc[2][1]);
            acc[2][2] = fmaf(a.z, b.z, acc[2][2]);
            acc[2][3] = fmaf(a.z, b.w, acc[2][3]);
            acc[3][0] = fmaf(a.w, b.x, acc[3][0]);
            acc[3][1] = fmaf(a.w, b.y, acc[3][1]);
            acc[3][2] = fmaf(a.w, b.z, acc[3][2]);
            acc[3][3] = fmaf(a.w, b.w, acc[3][3]);
        }
        __syncthreads();
    }

    float4 bv = *(const float4*)&bias[bn + tx * 4];
    #pragma unroll
    for (int i = 0; i < 4; i++) {
        int row = bm + ty * 4 + i;
        if (row >= M) continue;
        float4 c;
        c.x = acc[i][0] + bv.x;
        c.y = acc[i][1] + bv.y;
        c.z = acc[i][2] + bv.z;
        c.w = acc[i][3] + bv.w;
        if (RESID) {
            float4 r = *(const float4*)&resid[(size_t)row * Nn + bn + tx * 4];
            c.x += r.x; c.y += r.y; c.z += r.z; c.w += r.w;
        }
        *(float4*)&Co[(size_t)row * Nn + bn + tx * 4] = c;
    }
}

// ---------------------------------------------------------------------------
extern "C" void kernel_launch(void* const* d_in, const int* in_sizes, int n_in,
                              void* d_out, int out_size, void* d_ws, size_t ws_size,
                              hipStream_t stream)
{
    const float* x    = (const float*)d_in[0];
    const int*   ei   = (const int*)d_in[1];     // [2, E] int32
    const int*   srcE = ei;
    const int*   dstE = ei + NE;
    const float* bn_g = (const float*)d_in[2];
    const float* bn_b = (const float*)d_in[3];
    const float* W1   = (const float*)d_in[4];
    const float* b1   = (const float*)d_in[5];
    const float* g1   = (const float*)d_in[6];
    const float* be1  = (const float*)d_in[7];
    const float* W2   = (const float*)d_in[8];
    const float* b2   = (const float*)d_in[9];
    const float* g2   = (const float*)d_in[10];
    const float* be2  = (const float*)d_in[11];
    const float* W3   = (const float*)d_in[12];
    const float* b3   = (const float*)d_in[13];
    const float* We   = (const float*)d_in[14];
    const float* beb  = (const float*)d_in[15];
    float* out = (float*)d_out;

    float* ws = (float*)d_ws;
    // stats area (zeroed each call)
    float* sum0   = ws + 0;    float* sq0   = ws + 128;
    float* scale0 = ws + 256;  float* shift0 = ws + 384;
    float* sum1   = ws + 512;  float* sq1   = ws + 768;
    float* scale1 = ws + 1024; float* shift1 = ws + 1280;
    float* sum2   = ws + 1536; float* sq2   = ws + 1792;
    float* scale2 = ws + 2048; float* shift2 = ws + 2304;
    // big buffers, heavily aliased (lifetime notes):
    //   buf0: h            ; later t2 (t2 spans buf0+buf1)
    //   buf1: den -> a0    ; (agg reads den[i] then writes a0[i] at same index)
    //   buf2: (unused in edge phase) ; later t1 (t1 spans buf2+buf3); later y
    //   buf3: num
    float* buf0 = ws + 4096;
    float* buf1 = buf0 + NC;
    float* buf2 = buf1 + NC;
    float* buf3 = buf2 + NC;
    float* h   = buf0;
    float* den = buf1;
    float* num = buf3;
    float* a0  = buf1;              // in-place over den (safe: elementwise read-then-write)
    float* t1  = buf2;              // [N, 256] spans buf2+buf3 (num dead after agg)
    float* t2  = buf0;              // [N, 256] spans buf0+buf1 (h, a0 dead after gemm1... a0 read by gemm1 only)
    float* y   = buf2;              // [N, 128] over t1 after gemm2 reads it

    // zero: stats + den/num
    hipMemsetAsync(ws, 0, 4096 * sizeof(float), stream);
    hipMemsetAsync(buf1, 0, (size_t)NC * sizeof(float), stream);
    hipMemsetAsync(buf3, 0, (size_t)NC * sizeof(float), stream);

    // 1) outer BN stats + fold, h = relu(bn(x))
    stats_kernel<<<128, 256, 0, stream>>>(x, NN, CC, sum0, sq0);
    finalize_bn<<<1, 128, 0, stream>>>(sum0, sq0, bn_g, bn_b, scale0, shift0, NN, CC);
    bn_relu_kernel<<<(NC / 4 + 255) / 256, 256, 0, stream>>>(x, scale0, shift0, h, NC / 4);

    // 2) segment softmax-aggregation (shift-free: msg bounded, exp(msg) safe)
    int eThreads = NE * 32;
    edge_sum_kernel<<<(eThreads + 255) / 256, 256, 0, stream>>>(srcE, dstE, h, den, num);
    agg_kernel<<<(NC / 4 + 255) / 256, 256, 0, stream>>>(num, den, h, a0, NC / 4);

    const int MB = (NN + 63) / 64;
    // 3) MLP: t1 = a0 @ W1 + b1
    gemm_k<false, false><<<dim3(HD / 64, MB), 256, 0, stream>>>(
        a0, W1, b1, nullptr, nullptr, nullptr, t1, NN, CC, HD);
    stats_kernel<<<128, 256, 0, stream>>>(t1, NN, HD, sum1, sq1);
    finalize_bn<<<1, 256, 0, stream>>>(sum1, sq1, g1, be1, scale1, shift1, NN, HD);
    // t2 = relu(bn(t1)) @ W2 + b2
    gemm_k<true, false><<<dim3(HD / 64, MB), 256, 0, stream>>>(
        t1, W2, b2, scale1, shift1, nullptr, t2, NN, HD, HD);
    stats_kernel<<<128, 256, 0, stream>>>(t2, NN, HD, sum2, sq2);
    finalize_bn<<<1, 256, 0, stream>>>(sum2, sq2, g2, be2, scale2, shift2, NN, HD);
    // y = relu(bn(t2)) @ W3 + b3 + x   (residual fused)
    gemm_k<true, true><<<dim3(CC / 64, MB), 256, 0, stream>>>(
        t2, W3, b3, scale2, shift2, x, y, NN, HD, CC);
    // 4) out = y @ We + be
    gemm_k<false, false><<<dim3(CC / 64, MB), 256, 0, stream>>>(
        y, We, beb, nullptr, nullptr, nullptr, out, NN, CC, CC);
}

// Round 14
// 684.159 us; speedup vs baseline: 3.8319x; 3.8319x over previous
//
#include <hip/hip_runtime.h>
#include <cstddef>
#include <cstdint>

#define NN 50000          // nodes
#define NE 600000         // edges
#define CC 128            // in/out channels
#define HD 256            // MLP hidden
#define NC (NN * CC)      // floats per [N,128] buffer
#define EPS_GEN 1e-7f
#define EPS_BN  1e-5f

typedef __attribute__((ext_vector_type(8))) short short8;
typedef __attribute__((ext_vector_type(4))) float f32x4;

__device__ inline ushort f2bf(float f) {               // fp32 -> bf16 RNE
    uint u = __float_as_uint(f);
    return (ushort)((u + 0x7FFFu + ((u >> 16) & 1u)) >> 16);
}

// ---------------------------------------------------------------------------
// Column stats: per-column sum/sumsq partials, one atomicAdd pair per thread.
__global__ __launch_bounds__(256)
void stats_kernel(const float* __restrict__ A, int M, int Ncols,
                  float* __restrict__ sum, float* __restrict__ sumsq)
{
    int col = threadIdx.x % Ncols;
    int rowInBlock = threadIdx.x / Ncols;
    int rowsPerBlock = blockDim.x / Ncols;
    int step = rowsPerBlock * gridDim.x;
    float s = 0.f, q = 0.f;
    for (int r = blockIdx.x * rowsPerBlock + rowInBlock; r < M; r += step) {
        float v = A[(size_t)r * Ncols + col];
        s += v;
        q = fmaf(v, v, q);
    }
    atomicAdd(&sum[col], s);
    atomicAdd(&sumsq[col], q);
}

__global__ void finalize_bn(const float* __restrict__ sum,
                            const float* __restrict__ sumsq,
                            const float* __restrict__ g,
                            const float* __restrict__ b,
                            float* __restrict__ scale,
                            float* __restrict__ shift,
                            int M, int Ncols)
{
    int c = blockIdx.x * blockDim.x + threadIdx.x;
    if (c >= Ncols) return;
    float inv_m = 1.0f / (float)M;
    float mean = sum[c] * inv_m;
    float var  = sumsq[c] * inv_m - mean * mean;
    float v = var + EPS_BN;
    float rs = rsqrtf(v);
    rs = rs * (1.5f - 0.5f * v * rs * rs);   // Newton step
    float sc = g[c] * rs;
    scale[c] = sc;
    shift[c] = b[c] - mean * sc;
}

// dst = relu(src*scale + shift); src/dst may alias (elementwise).
template <int NCOL>
__global__ __launch_bounds__(256)
void bnrelu_kernel(const float* __restrict__ src,
                   const float* __restrict__ scale,
                   const float* __restrict__ shift,
                   float* __restrict__ dst, int total4)
{
    int tid = blockIdx.x * blockDim.x + threadIdx.x;
    if (tid >= total4) return;
    int c4 = tid & (NCOL / 4 - 1);
    float4 sc = ((const float4*)scale)[c4];
    float4 sh = ((const float4*)shift)[c4];
    float4 v  = ((const float4*)src)[tid];
    float4 o;
    o.x = fmaxf(fmaf(v.x, sc.x, sh.x), 0.f);
    o.y = fmaxf(fmaf(v.y, sc.y, sh.y), 0.f);
    o.z = fmaxf(fmaf(v.z, sc.z, sh.z), 0.f);
    o.w = fmaxf(fmaf(v.w, sc.w, sh.w), 0.f);
    ((float4*)dst)[tid] = o;
}

// ---------------------------------------------------------------------------
// CSR build
__global__ __launch_bounds__(256)
void hist_kernel(const int* __restrict__ dst, int* __restrict__ deg)
{
    int e = blockIdx.x * blockDim.x + threadIdx.x;
    if (e < NE) atomicAdd(&deg[dst[e]], 1);
}

__global__ __launch_bounds__(1024)
void scan_kernel(const int* __restrict__ deg, int* __restrict__ rowptr, int n)
{
    __shared__ int wsum[16];
    __shared__ int woff[16];
    int lane = threadIdx.x & 63, wid = threadIdx.x >> 6;
    if (threadIdx.x == 0) rowptr[0] = 0;
    int carry = 0;
    for (int base = 0; base < n; base += 1024) {
        int i = base + threadIdx.x;
        int v = (i < n) ? deg[i] : 0;
        int s = v;
        #pragma unroll
        for (int off = 1; off < 64; off <<= 1) {
            int t = __shfl_up(s, off, 64);
            if (lane >= off) s += t;
        }
        if (lane == 63) wsum[wid] = s;
        __syncthreads();
        if (wid == 0) {
            int ws = (lane < 16) ? wsum[lane] : 0;
            #pragma unroll
            for (int off = 1; off < 16; off <<= 1) {
                int t = __shfl_up(ws, off, 64);
                if (lane >= off) ws += t;
            }
            if (lane < 16) woff[lane] = ws;
        }
        __syncthreads();
        int blockoff = (wid > 0) ? woff[wid - 1] : 0;
        if (i < n) rowptr[i + 1] = carry + s + blockoff;
        carry += woff[15];
        __syncthreads();
    }
}

__global__ __launch_bounds__(256)
void scatter_kernel(const int* __restrict__ src, const int* __restrict__ dst,
                    const int* __restrict__ rowptr, int* __restrict__ cursor,
                    int* __restrict__ col)
{
    int e = blockIdx.x * blockDim.x + threadIdx.x;
    if (e >= NE) return;
    int d = dst[e];
    int pos = atomicAdd(&cursor[d], 1);
    col[rowptr[d] + pos] = src[e];
}

// Per-node softmax aggregation + root add (shift-free: msg bounded).
__global__ __launch_bounds__(128)
void csr_agg_kernel(const int* __restrict__ rowptr, const int* __restrict__ col,
                    const float* __restrict__ h, float* __restrict__ a0)
{
    int node = blockIdx.x;
    int c = threadIdx.x;
    int beg = rowptr[node], end = rowptr[node + 1];
    float den = 0.f, num = 0.f;
    for (int j = beg; j < end; j++) {
        int s = col[j];
        float msg = h[(size_t)s * CC + c] + EPS_GEN;
        float ex = __expf(msg);
        den += ex;
        num = fmaf(msg, ex, num);
    }
    float hv = h[(size_t)node * CC + c];
    a0[(size_t)node * CC + c] = num / (den + 1e-16f) + hv;
}

// ---------------------------------------------------------------------------
// bf16 MFMA GEMM: C[M,Nn] = A[M,K] @ B[K,Nn] + bias (+ resid)
// 64x64 tile, BK=32, 256 thr / 4 waves, each wave 32x32 via 2x2 16x16x32 MFMA.
// A fp32 global -> bf16 LDS (XOR-swizzled); B fp32 [K][N] -> transposed bf16 LDS.
// Fragment convention (permutation-safe): lane&15 = frag row/col, lane>>4 = kgrp,
// 8 contiguous k per lane. C/D: col=lane&15, row=4*(lane>>4)+reg  [HW-verified].
template <bool RESID>
__global__ __launch_bounds__(256)
void gemm_bf16(const float* __restrict__ A, const float* __restrict__ B,
               const float* __restrict__ bias, const float* __restrict__ resid,
               float* __restrict__ C, int M, int K, int Nn)
{
    __shared__ __align__(16) ushort As[64 * 32];
    __shared__ __align__(16) ushort Bs[64 * 32];
    const int bm = blockIdx.y * 64, bn = blockIdx.x * 64;
    const int t = threadIdx.x;
    const int w = t >> 6, lane = t & 63;
    const int wr = w >> 1, wc = w & 1;
    const int l16 = lane & 15, g = lane >> 4;

    f32x4 acc[2][2];
    #pragma unroll
    for (int i = 0; i < 2; i++)
        #pragma unroll
        for (int j = 0; j < 2; j++) {
            f32x4 z = {0.f, 0.f, 0.f, 0.f};
            acc[i][j] = z;
        }

    for (int k0 = 0; k0 < K; k0 += 32) {
        // stage A: 64 rows x 32 k (fp32 -> bf16), float4 loads, uint2 LDS writes
        #pragma unroll
        for (int p = 0; p < 2; p++) {
            int rl = (t >> 3) + 32 * p;          // 0..63
            int kc = (t & 7) * 4;                // 0,4,...,28
            int row = bm + rl;
            float4 v = {0.f, 0.f, 0.f, 0.f};
            if (row < M) v = *(const float4*)&A[(size_t)row * K + k0 + kc];
            uint lo = (uint)f2bf(v.x) | ((uint)f2bf(v.y) << 16);
            uint hi = (uint)f2bf(v.z) | ((uint)f2bf(v.w) << 16);
            int el = (rl * 32 + kc) ^ ((rl & 7) << 3);
            *(uint2*)&As[el] = make_uint2(lo, hi);
        }
        // stage B transposed: Bs[n][k] <- B[k0+kk][bn+n]
        {
            int n = t & 63, kk0 = t >> 6;
            #pragma unroll
            for (int i = 0; i < 8; i++) {
                int kk = kk0 + 4 * i;
                ushort bv = f2bf(B[(size_t)(k0 + kk) * Nn + bn + n]);
                int el = (n * 32 + kk) ^ ((n & 7) << 3);
                Bs[el] = bv;
            }
        }
        __syncthreads();

        short8 af[2], bfr[2];
        #pragma unroll
        for (int fm = 0; fm < 2; fm++) {
            int m = 32 * wr + 16 * fm + l16;
            int el = (m * 32 + 8 * g) ^ ((m & 7) << 3);
            af[fm] = *(const short8*)&As[el];
        }
        #pragma unroll
        for (int fn = 0; fn < 2; fn++) {
            int n = 32 * wc + 16 * fn + l16;
            int el = (n * 32 + 8 * g) ^ ((n & 7) << 3);
            bfr[fn] = *(const short8*)&Bs[el];
        }
        #pragma unroll
        for (int fm = 0; fm < 2; fm++)
            #pragma unroll
            for (int fn = 0; fn < 2; fn++)
                acc[fm][fn] = __builtin_amdgcn_mfma_f32_16x16x32_bf16(
                    af[fm], bfr[fn], acc[fm][fn], 0, 0, 0);
        __syncthreads();
    }

    // epilogue: D col = lane&15, row = 4*(lane>>4)+reg  [m89/m91 verified]
    #pragma unroll
    for (int fn = 0; fn < 2; fn++) {
        int colg = bn + 32 * wc + 16 * fn + l16;
        float bv = bias[colg];
        #pragma unroll
        for (int fm = 0; fm < 2; fm++) {
            #pragma unroll
            for (int r = 0; r < 4; r++) {
                int row = bm + 32 * wr + 16 * fm + 4 * g + r;
                if (row < M) {
                    float val = acc[fm][fn][r] + bv;
                    if (RESID) val += resid[(size_t)row * Nn + colg];
                    C[(size_t)row * Nn + colg] = val;
                }
            }
        }
    }
}

// ---------------------------------------------------------------------------
extern "C" void kernel_launch(void* const* d_in, const int* in_sizes, int n_in,
                              void* d_out, int out_size, void* d_ws, size_t ws_size,
                              hipStream_t stream)
{
    const float* x    = (const float*)d_in[0];
    const int*   ei   = (const int*)d_in[1];
    const int*   srcE = ei;
    const int*   dstE = ei + NE;
    const float* bn_g = (const float*)d_in[2];
    const float* bn_b = (const float*)d_in[3];
    const float* W1   = (const float*)d_in[4];
    const float* b1   = (const float*)d_in[5];
    const float* g1   = (const float*)d_in[6];
    const float* be1  = (const float*)d_in[7];
    const float* W2   = (const float*)d_in[8];
    const float* b2   = (const float*)d_in[9];
    const float* g2   = (const float*)d_in[10];
    const float* be2  = (const float*)d_in[11];
    const float* W3   = (const float*)d_in[12];
    const float* b3   = (const float*)d_in[13];
    const float* We   = (const float*)d_in[14];
    const float* beb  = (const float*)d_in[15];
    float* out = (float*)d_out;

    float* ws = (float*)d_ws;
    float* sum0   = ws + 0;    float* sq0    = ws + 128;
    float* scale0 = ws + 256;  float* shift0 = ws + 384;
    float* sum1   = ws + 512;  float* sq1    = ws + 768;
    float* scale1 = ws + 1024; float* shift1 = ws + 1280;
    float* sum2   = ws + 1536; float* sq2    = ws + 1792;
    float* scale2 = ws + 2048; float* shift2 = ws + 2304;
    // buf0: h -> t2.lo   buf1: a0 -> t2.hi   buf2: CSR -> t1.lo -> y   buf3: t1.hi
    float* buf0 = ws + 4096;
    float* buf1 = buf0 + NC;
    float* buf2 = buf1 + NC;
    float* buf3 = buf2 + NC;
    float* h  = buf0;
    float* a0 = buf1;
    float* t1 = buf2;   // [N,256] spans buf2+buf3
    float* t2 = buf0;   // [N,256] spans buf0+buf1
    float* y  = buf2;   // [N,128]
    (void)buf3;

    int* ipool  = (int*)buf2;
    int* deg    = ipool;
    int* cursor = ipool + 50176;
    int* rowptr = ipool + 100352;
    int* col    = ipool + 151040;

    hipMemsetAsync(ws, 0, 4096 * sizeof(float), stream);
    hipMemsetAsync(ipool, 0, 100352 * sizeof(int), stream);

    // 1) outer BN + ReLU
    stats_kernel<<<128, 256, 0, stream>>>(x, NN, CC, sum0, sq0);
    finalize_bn<<<1, 128, 0, stream>>>(sum0, sq0, bn_g, bn_b, scale0, shift0, NN, CC);
    bnrelu_kernel<CC><<<(NC / 4 + 255) / 256, 256, 0, stream>>>(x, scale0, shift0, h, NC / 4);

    // 2) CSR build + gather-side softmax aggregation
    hist_kernel<<<(NE + 255) / 256, 256, 0, stream>>>(dstE, deg);
    scan_kernel<<<1, 1024, 0, stream>>>(deg, rowptr, NN);
    scatter_kernel<<<(NE + 255) / 256, 256, 0, stream>>>(srcE, dstE, rowptr, cursor, col);
    csr_agg_kernel<<<NN, 128, 0, stream>>>(rowptr, col, h, a0);

    const int MB = (NN + 63) / 64;
    const int NC2 = NN * HD;
    // 3) MLP with bf16 MFMA GEMMs, BN+ReLU as separate passes
    gemm_bf16<false><<<dim3(HD / 64, MB), 256, 0, stream>>>(
        a0, W1, b1, nullptr, t1, NN, CC, HD);
    stats_kernel<<<128, 256, 0, stream>>>(t1, NN, HD, sum1, sq1);
    finalize_bn<<<1, 256, 0, stream>>>(sum1, sq1, g1, be1, scale1, shift1, NN, HD);
    bnrelu_kernel<HD><<<(NC2 / 4 + 255) / 256, 256, 0, stream>>>(t1, scale1, shift1, t1, NC2 / 4);

    gemm_bf16<false><<<dim3(HD / 64, MB), 256, 0, stream>>>(
        t1, W2, b2, nullptr, t2, NN, HD, HD);
    stats_kernel<<<128, 256, 0, stream>>>(t2, NN, HD, sum2, sq2);
    finalize_bn<<<1, 256, 0, stream>>>(sum2, sq2, g2, be2, scale2, shift2, NN, HD);
    bnrelu_kernel<HD><<<(NC2 / 4 + 255) / 256, 256, 0, stream>>>(t2, scale2, shift2, t2, NC2 / 4);

    // y = bnrelu(t2) @ W3 + b3 + x
    gemm_bf16<true><<<dim3(CC / 64, MB), 256, 0, stream>>>(
        t2, W3, b3, x, y, NN, HD, CC);
    // out = y @ We + be
    gemm_bf16<false><<<dim3(CC / 64, MB), 256, 0, stream>>>(
        y, We, beb, nullptr, out, NN, CC, CC);
}

// Round 15
// 604.795 us; speedup vs baseline: 4.3348x; 1.1312x over previous
//
#include <hip/hip_runtime.h>
#include <cstddef>
#include <cstdint>

#define NN 50000          // nodes
#define NE 600000         // edges
#define CC 128            // in/out channels
#define HD 256            // MLP hidden
#define NC (NN * CC)      // floats per [N,128] buffer
#define EPS_GEN 1e-7f
#define EPS_BN  1e-5f

typedef __attribute__((ext_vector_type(8))) short short8;
typedef __attribute__((ext_vector_type(4))) float f32x4;

__device__ inline ushort f2bf(float f) {               // fp32 -> bf16 RNE
    uint u = __float_as_uint(f);
    return (ushort)((u + 0x7FFFu + ((u >> 16) & 1u)) >> 16);
}

// ---------------------------------------------------------------------------
// Column stats, vectorized: float4 loads, LDS tree reduction over rows,
// one atomic set per (block, column). 512 blocks -> high TLP (was 128 blocks
// scalar: 5.3% occupancy, 97us). NCOL in {128, 256}.
template <int NCOL>
__global__ __launch_bounds__(256)
void stats4_kernel(const float* __restrict__ A, int M,
                   float* __restrict__ sum, float* __restrict__ sumsq)
{
    constexpr int G = NCOL / 4;        // float4 groups per row (32 or 64)
    constexpr int R = 256 / G;         // rows per block-iteration (8 or 4)
    __shared__ float4 s_lds[256];
    __shared__ float4 q_lds[256];
    const int c = threadIdx.x % G;
    const int r = threadIdx.x / G;
    float4 s = {0.f, 0.f, 0.f, 0.f}, q = {0.f, 0.f, 0.f, 0.f};
    const int step = R * gridDim.x;
    for (int row = blockIdx.x * R + r; row < M; row += step) {
        float4 v = ((const float4*)(A + (size_t)row * NCOL))[c];
        s.x += v.x; s.y += v.y; s.z += v.z; s.w += v.w;
        q.x = fmaf(v.x, v.x, q.x);
        q.y = fmaf(v.y, v.y, q.y);
        q.z = fmaf(v.z, v.z, q.z);
        q.w = fmaf(v.w, v.w, q.w);
    }
    s_lds[threadIdx.x] = s;
    q_lds[threadIdx.x] = q;
    __syncthreads();
    #pragma unroll
    for (int st = R / 2; st > 0; st >>= 1) {
        if (r < st) {
            float4 s2 = s_lds[threadIdx.x + st * G];
            float4 q2 = q_lds[threadIdx.x + st * G];
            s.x += s2.x; s.y += s2.y; s.z += s2.z; s.w += s2.w;
            q.x += q2.x; q.y += q2.y; q.z += q2.z; q.w += q2.w;
            s_lds[threadIdx.x] = s;
            q_lds[threadIdx.x] = q;
        }
        __syncthreads();
    }
    if (r == 0) {
        atomicAdd(&sum[c * 4 + 0], s.x);
        atomicAdd(&sum[c * 4 + 1], s.y);
        atomicAdd(&sum[c * 4 + 2], s.z);
        atomicAdd(&sum[c * 4 + 3], s.w);
        atomicAdd(&sumsq[c * 4 + 0], q.x);
        atomicAdd(&sumsq[c * 4 + 1], q.y);
        atomicAdd(&sumsq[c * 4 + 2], q.z);
        atomicAdd(&sumsq[c * 4 + 3], q.w);
    }
}

__global__ void finalize_bn(const float* __restrict__ sum,
                            const float* __restrict__ sumsq,
                            const float* __restrict__ g,
                            const float* __restrict__ b,
                            float* __restrict__ scale,
                            float* __restrict__ shift,
                            int M, int Ncols)
{
    int c = blockIdx.x * blockDim.x + threadIdx.x;
    if (c >= Ncols) return;
    float inv_m = 1.0f / (float)M;
    float mean = sum[c] * inv_m;
    float var  = sumsq[c] * inv_m - mean * mean;
    float v = var + EPS_BN;
    float rs = rsqrtf(v);
    rs = rs * (1.5f - 0.5f * v * rs * rs);   // Newton step
    float sc = g[c] * rs;
    scale[c] = sc;
    shift[c] = b[c] - mean * sc;
}

// dst = relu(src*scale + shift)  (used only for h = relu(bn(x)))
template <int NCOL>
__global__ __launch_bounds__(256)
void bnrelu_kernel(const float* __restrict__ src,
                   const float* __restrict__ scale,
                   const float* __restrict__ shift,
                   float* __restrict__ dst, int total4)
{
    int tid = blockIdx.x * blockDim.x + threadIdx.x;
    if (tid >= total4) return;
    int c4 = tid & (NCOL / 4 - 1);
    float4 sc = ((const float4*)scale)[c4];
    float4 sh = ((const float4*)shift)[c4];
    float4 v  = ((const float4*)src)[tid];
    float4 o;
    o.x = fmaxf(fmaf(v.x, sc.x, sh.x), 0.f);
    o.y = fmaxf(fmaf(v.y, sc.y, sh.y), 0.f);
    o.z = fmaxf(fmaf(v.z, sc.z, sh.z), 0.f);
    o.w = fmaxf(fmaf(v.w, sc.w, sh.w), 0.f);
    ((float4*)dst)[tid] = o;
}

// ---------------------------------------------------------------------------
// CSR build
__global__ __launch_bounds__(256)
void hist_kernel(const int* __restrict__ dst, int* __restrict__ deg)
{
    int e = blockIdx.x * blockDim.x + threadIdx.x;
    if (e < NE) atomicAdd(&deg[dst[e]], 1);
}

__global__ __launch_bounds__(1024)
void scan_kernel(const int* __restrict__ deg, int* __restrict__ rowptr, int n)
{
    __shared__ int wsum[16];
    __shared__ int woff[16];
    int lane = threadIdx.x & 63, wid = threadIdx.x >> 6;
    if (threadIdx.x == 0) rowptr[0] = 0;
    int carry = 0;
    for (int base = 0; base < n; base += 1024) {
        int i = base + threadIdx.x;
        int v = (i < n) ? deg[i] : 0;
        int s = v;
        #pragma unroll
        for (int off = 1; off < 64; off <<= 1) {
            int t = __shfl_up(s, off, 64);
            if (lane >= off) s += t;
        }
        if (lane == 63) wsum[wid] = s;
        __syncthreads();
        if (wid == 0) {
            int ws = (lane < 16) ? wsum[lane] : 0;
            #pragma unroll
            for (int off = 1; off < 16; off <<= 1) {
                int t = __shfl_up(ws, off, 64);
                if (lane >= off) ws += t;
            }
            if (lane < 16) woff[lane] = ws;
        }
        __syncthreads();
        int blockoff = (wid > 0) ? woff[wid - 1] : 0;
        if (i < n) rowptr[i + 1] = carry + s + blockoff;
        carry += woff[15];
        __syncthreads();
    }
}

__global__ __launch_bounds__(256)
void scatter_kernel(const int* __restrict__ src, const int* __restrict__ dst,
                    const int* __restrict__ rowptr, int* __restrict__ cursor,
                    int* __restrict__ col)
{
    int e = blockIdx.x * blockDim.x + threadIdx.x;
    if (e >= NE) return;
    int d = dst[e];
    int pos = atomicAdd(&cursor[d], 1);
    col[rowptr[d] + pos] = src[e];
}

// Per-node softmax aggregation + root add (shift-free: msg bounded).
__global__ __launch_bounds__(128)
void csr_agg_kernel(const int* __restrict__ rowptr, const int* __restrict__ col,
                    const float* __restrict__ h, float* __restrict__ a0)
{
    int node = blockIdx.x;
    int c = threadIdx.x;
    int beg = rowptr[node], end = rowptr[node + 1];
    float den = 0.f, num = 0.f;
    for (int j = beg; j < end; j++) {
        int s = col[j];
        float msg = h[(size_t)s * CC + c] + EPS_GEN;
        float ex = __expf(msg);
        den += ex;
        num = fmaf(msg, ex, num);
    }
    float hv = h[(size_t)node * CC + c];
    a0[(size_t)node * CC + c] = num / (den + 1e-16f) + hv;
}

// ---------------------------------------------------------------------------
// bf16 MFMA GEMM: C[M,Nn] = op(A)[M,K] @ B[K,Nn] + bias (+ resid)
// op(A) = relu(A*asc[k]+ash[k]) when TRANSA (fused BN+ReLU on A operand).
// 64x64 tile, BK=32, 256 thr / 4 waves, each wave 32x32 via 2x2 16x16x32 MFMA.
// Fragment convention (permutation-safe): lane&15 = frag row/col, lane>>4 = kgrp,
// 8 contiguous k per lane. C/D: col=lane&15, row=4*(lane>>4)+reg  [HW-verified].
template <bool TRANSA, bool RESID>
__global__ __launch_bounds__(256)
void gemm_bf16(const float* __restrict__ A, const float* __restrict__ B,
               const float* __restrict__ bias,
               const float* __restrict__ asc, const float* __restrict__ ash,
               const float* __restrict__ resid,
               float* __restrict__ C, int M, int K, int Nn)
{
    __shared__ __align__(16) ushort As[64 * 32];
    __shared__ __align__(16) ushort Bs[64 * 32];
    const int bm = blockIdx.y * 64, bn = blockIdx.x * 64;
    const int t = threadIdx.x;
    const int w = t >> 6, lane = t & 63;
    const int wr = w >> 1, wc = w & 1;
    const int l16 = lane & 15, g = lane >> 4;

    f32x4 acc[2][2];
    #pragma unroll
    for (int i = 0; i < 2; i++)
        #pragma unroll
        for (int j = 0; j < 2; j++) {
            f32x4 z = {0.f, 0.f, 0.f, 0.f};
            acc[i][j] = z;
        }

    for (int k0 = 0; k0 < K; k0 += 32) {
        // stage A: 64 rows x 32 k (fp32 -> bf16), float4 loads, uint2 LDS writes
        #pragma unroll
        for (int p = 0; p < 2; p++) {
            int rl = (t >> 3) + 32 * p;          // 0..63
            int kc = (t & 7) * 4;                // 0,4,...,28
            int row = bm + rl;
            float4 v = {0.f, 0.f, 0.f, 0.f};
            if (row < M) v = *(const float4*)&A[(size_t)row * K + k0 + kc];
            if (TRANSA) {
                float4 sc = *(const float4*)&asc[k0 + kc];
                float4 sh = *(const float4*)&ash[k0 + kc];
                v.x = fmaxf(fmaf(v.x, sc.x, sh.x), 0.f);
                v.y = fmaxf(fmaf(v.y, sc.y, sh.y), 0.f);
                v.z = fmaxf(fmaf(v.z, sc.z, sh.z), 0.f);
                v.w = fmaxf(fmaf(v.w, sc.w, sh.w), 0.f);
            }
            uint lo = (uint)f2bf(v.x) | ((uint)f2bf(v.y) << 16);
            uint hi = (uint)f2bf(v.z) | ((uint)f2bf(v.w) << 16);
            int el = (rl * 32 + kc) ^ ((rl & 7) << 3);
            *(uint2*)&As[el] = make_uint2(lo, hi);
        }
        // stage B transposed: Bs[n][k] <- B[k0+kk][bn+n]
        {
            int n = t & 63, kk0 = t >> 6;
            #pragma unroll
            for (int i = 0; i < 8; i++) {
                int kk = kk0 + 4 * i;
                ushort bv = f2bf(B[(size_t)(k0 + kk) * Nn + bn + n]);
                int el = (n * 32 + kk) ^ ((n & 7) << 3);
                Bs[el] = bv;
            }
        }
        __syncthreads();

        short8 af[2], bfr[2];
        #pragma unroll
        for (int fm = 0; fm < 2; fm++) {
            int m = 32 * wr + 16 * fm + l16;
            int el = (m * 32 + 8 * g) ^ ((m & 7) << 3);
            af[fm] = *(const short8*)&As[el];
        }
        #pragma unroll
        for (int fn = 0; fn < 2; fn++) {
            int n = 32 * wc + 16 * fn + l16;
            int el = (n * 32 + 8 * g) ^ ((n & 7) << 3);
            bfr[fn] = *(const short8*)&Bs[el];
        }
        #pragma unroll
        for (int fm = 0; fm < 2; fm++)
            #pragma unroll
            for (int fn = 0; fn < 2; fn++)
                acc[fm][fn] = __builtin_amdgcn_mfma_f32_16x16x32_bf16(
                    af[fm], bfr[fn], acc[fm][fn], 0, 0, 0);
        __syncthreads();
    }

    // epilogue: D col = lane&15, row = 4*(lane>>4)+reg  [m89/m91 verified]
    #pragma unroll
    for (int fn = 0; fn < 2; fn++) {
        int colg = bn + 32 * wc + 16 * fn + l16;
        float bv = bias[colg];
        #pragma unroll
        for (int fm = 0; fm < 2; fm++) {
            #pragma unroll
            for (int r = 0; r < 4; r++) {
                int row = bm + 32 * wr + 16 * fm + 4 * g + r;
                if (row < M) {
                    float val = acc[fm][fn][r] + bv;
                    if (RESID) val += resid[(size_t)row * Nn + colg];
                    C[(size_t)row * Nn + colg] = val;
                }
            }
        }
    }
}

// ---------------------------------------------------------------------------
extern "C" void kernel_launch(void* const* d_in, const int* in_sizes, int n_in,
                              void* d_out, int out_size, void* d_ws, size_t ws_size,
                              hipStream_t stream)
{
    const float* x    = (const float*)d_in[0];
    const int*   ei   = (const int*)d_in[1];
    const int*   srcE = ei;
    const int*   dstE = ei + NE;
    const float* bn_g = (const float*)d_in[2];
    const float* bn_b = (const float*)d_in[3];
    const float* W1   = (const float*)d_in[4];
    const float* b1   = (const float*)d_in[5];
    const float* g1   = (const float*)d_in[6];
    const float* be1  = (const float*)d_in[7];
    const float* W2   = (const float*)d_in[8];
    const float* b2   = (const float*)d_in[9];
    const float* g2   = (const float*)d_in[10];
    const float* be2  = (const float*)d_in[11];
    const float* W3   = (const float*)d_in[12];
    const float* b3   = (const float*)d_in[13];
    const float* We   = (const float*)d_in[14];
    const float* beb  = (const float*)d_in[15];
    float* out = (float*)d_out;

    float* ws = (float*)d_ws;
    float* sum0   = ws + 0;    float* sq0    = ws + 128;
    float* scale0 = ws + 256;  float* shift0 = ws + 384;
    float* sum1   = ws + 512;  float* sq1    = ws + 768;
    float* scale1 = ws + 1024; float* shift1 = ws + 1280;
    float* sum2   = ws + 1536; float* sq2    = ws + 1792;
    float* scale2 = ws + 2048; float* shift2 = ws + 2304;
    // buf0: h -> t2.lo   buf1: a0 -> t2.hi   buf2: CSR -> t1.lo -> y   buf3: t1.hi
    float* buf0 = ws + 4096;
    float* buf1 = buf0 + NC;
    float* buf2 = buf1 + NC;
    float* buf3 = buf2 + NC;
    float* h  = buf0;
    float* a0 = buf1;
    float* t1 = buf2;   // [N,256] spans buf2+buf3
    float* t2 = buf0;   // [N,256] spans buf0+buf1
    float* y  = buf2;   // [N,128]
    (void)buf3;

    int* ipool  = (int*)buf2;
    int* deg    = ipool;
    int* cursor = ipool + 50176;
    int* rowptr = ipool + 100352;
    int* col    = ipool + 151040;

    hipMemsetAsync(ws, 0, 4096 * sizeof(float), stream);
    hipMemsetAsync(ipool, 0, 100352 * sizeof(int), stream);

    // 1) outer BN + ReLU (h must be materialized for the edge gather)
    stats4_kernel<CC><<<512, 256, 0, stream>>>(x, NN, sum0, sq0);
    finalize_bn<<<1, 128, 0, stream>>>(sum0, sq0, bn_g, bn_b, scale0, shift0, NN, CC);
    bnrelu_kernel<CC><<<(NC / 4 + 255) / 256, 256, 0, stream>>>(x, scale0, shift0, h, NC / 4);

    // 2) CSR build + gather-side softmax aggregation
    hist_kernel<<<(NE + 255) / 256, 256, 0, stream>>>(dstE, deg);
    scan_kernel<<<1, 1024, 0, stream>>>(deg, rowptr, NN);
    scatter_kernel<<<(NE + 255) / 256, 256, 0, stream>>>(srcE, dstE, rowptr, cursor, col);
    csr_agg_kernel<<<NN, 128, 0, stream>>>(rowptr, col, h, a0);

    const int MB = (NN + 63) / 64;
    // 3) MLP: bf16 MFMA GEMMs with BN+ReLU fused into A-staging
    gemm_bf16<false, false><<<dim3(HD / 64, MB), 256, 0, stream>>>(
        a0, W1, b1, nullptr, nullptr, nullptr, t1, NN, CC, HD);
    stats4_kernel<HD><<<512, 256, 0, stream>>>(t1, NN, sum1, sq1);
    finalize_bn<<<1, 256, 0, stream>>>(sum1, sq1, g1, be1, scale1, shift1, NN, HD);

    gemm_bf16<true, false><<<dim3(HD / 64, MB), 256, 0, stream>>>(
        t1, W2, b2, scale1, shift1, nullptr, t2, NN, HD, HD);
    stats4_kernel<HD><<<512, 256, 0, stream>>>(t2, NN, sum2, sq2);
    finalize_bn<<<1, 256, 0, stream>>>(sum2, sq2, g2, be2, scale2, shift2, NN, HD);

    // y = relu(bn(t2)) @ W3 + b3 + x
    gemm_bf16<true, true><<<dim3(CC / 64, MB), 256, 0, stream>>>(
        t2, W3, b3, scale2, shift2, x, y, NN, HD, CC);
    // out = y @ We + be
    gemm_bf16<false, false><<<dim3(CC / 64, MB), 256, 0, stream>>>(
        y, We, beb, nullptr, nullptr, nullptr, out, NN, CC, CC);
}